// Round 15
// baseline (234.174 us; speedup 1.0000x reference)
//
#include <hip/hip_runtime.h>
#include <math.h>

#define N_B 4
#define SEQ 2048
#define DM  512
#define H_N 8
#define DH  64

typedef unsigned short ushort_t;
typedef __attribute__((ext_vector_type(8))) short short8_t;
typedef __attribute__((ext_vector_type(4))) float float4_t;

#define LOG2E 1.4426950408889634074f

__device__ __forceinline__ ushort_t f2bf(float f) {
    unsigned int x = __float_as_uint(f);
    unsigned int lsb = (x >> 16) & 1u;
    x += 0x7fffu + lsb;
    return (ushort_t)(x >> 16);
}
__device__ __forceinline__ unsigned int cvtpk_bf16(float a, float b) {
    unsigned int r;
    asm("v_cvt_pk_bf16_f32 %0, %1, %2" : "=v"(r) : "v"(a), "v"(b));
    return r;   // lo = bf16(a), hi = bf16(b), RNE
}
__device__ __forceinline__ float fexp2(float x) {
#if __has_builtin(__builtin_amdgcn_exp2f)
    return __builtin_amdgcn_exp2f(x);
#else
    return exp2f(x);
#endif
}

// Merged pre-pass: query + 4 weights -> bf16 (RNE); bias concat; sigmoid bias table.
// Wq/Wk/Wv output channels PERMUTED head-major: c' = (c&7)*64 + (c>>3), so mgemm<0>
// output col c' decodes hh=c'>>6, dh=c'&63 (coalescable stores). bcat permuted to match.
#define Q4 1048576   // query float4 groups
#define W4 65536     // per-weight float4 groups
#define RELN 4095    // 2*SEQ-1
#define GTABN (H_N * RELN)
__global__ __launch_bounds__(256)
void prep(const float* __restrict__ query,
          const float* __restrict__ Wq, const float* __restrict__ Wk,
          const float* __restrict__ Wv, const float* __restrict__ Wp,
          const float* __restrict__ bq, const float* __restrict__ bk,
          const float* __restrict__ bv, const float* __restrict__ bp,
          const float* __restrict__ rpe,
          ushort_t* __restrict__ q16, ushort_t* __restrict__ w16,
          float* __restrict__ bcat, float* __restrict__ gtab)
{
    int i = blockIdx.x * 256 + threadIdx.x;
    if (i < Q4) {
        float4 x = ((const float4*)query)[i];
        uint2 p;
        p.x = cvtpk_bf16(x.x, x.y);
        p.y = cvtpk_bf16(x.z, x.w);
        ((uint2*)q16)[i] = p;
    } else if (i < Q4 + 4 * W4) {
        int wi = i - Q4;
        int w = wi >> 16;
        const float* W = (w == 0) ? Wq : (w == 1) ? Wk : (w == 2) ? Wv : Wp;
        int gwi = wi & (W4 - 1);
        int c = gwi >> 7;            // original output channel 0..511
        int g = gwi & 127;           // float4 group within row
        float4 x = ((const float4*)W)[gwi];
        uint2 p;
        p.x = cvtpk_bf16(x.x, x.y);
        p.y = cvtpk_bf16(x.z, x.w);
        int c2 = (w < 3) ? (((c & 7) << 6) | (c >> 3)) : c;   // head-major permute
        ((uint2*)w16)[w * W4 + c2 * 128 + g] = p;
    } else if (i < Q4 + 4 * W4 + 2048) {
        int bi = i - (Q4 + 4 * W4);
        int seg = bi >> 9;
        int c = bi & 511;
        const float* B = (seg == 0) ? bq : (seg == 1) ? bk : (seg == 2) ? bv : bp;
        int c2 = (seg < 3) ? (((c & 7) << 6) | (c >> 3)) : c;
        bcat[seg * 512 + c2] = B[c];
    } else {
        int gi = i - (Q4 + 4 * W4 + 2048);
        if (gi < GTABN) {
            int h = gi / RELN;
            int rel = gi - h * RELN;
            float4 v;
            #pragma unroll
            for (int c = 0; c < 4; c++) {
                int rr = rel - c;
                if (rr < 0) rr = 0;                  // components never consumed when rel<3
                float x = rpe[rr * H_N + h];
                ((float*)&v)[c] = LOG2E / (1.0f + __expf(-x));
            }
            ((float4*)gtab)[gi] = v;
        }
    }
}

// Single-pass bf16 MFMA GEMM. Round-15: T14 register-prefetch staging replaces
// global_load_lds + vmcnt(0) drain: issue tile k+1 global loads into regs BEFORE
// computing tile k, then barrier -> ds_write -> barrier. The HBM/L2 load latency
// (~200-900cy) hides under the 32-MFMA compute + 12 waves/CU TLP instead of
// sitting in a full vmcnt(0) drain between the two barriers (K=512 gives only
// 8 iterations to amortize it). LDS layout UNCHANGED: lane l -> row l>>3,
// chunk l&7, with global source chunk gchk = (l&7)^((l>>3)&7) (XOR-8 swizzle),
// matching the gload_lds base+lane*16 placement the fragment reads expect.
// C[m,c] = sum_k A[m,k]*W[c,k] + bias[c]
// MODE 0: LDS-staged coalesced epilogue (q/k straight, vt transposed), W head-major.
// MODE 1: fp32 out [m][512] direct.
template<int MODE>
__global__ __launch_bounds__(256)
void mgemm(const ushort_t* __restrict__ A, const ushort_t* __restrict__ B,
           const float* __restrict__ bias,
           ushort_t* __restrict__ q_o, ushort_t* __restrict__ k_o,
           ushort_t* __restrict__ vt_o, float* __restrict__ p_o)
{
    __shared__ __align__(16) union SM {
        struct { ushort_t A[128][64]; ushort_t B[128][64]; } ab;   // 32 KB staging
        ushort_t C[128][128];                                      // 32 KB epilogue tile
    } sm;
    ushort_t (&As)[128][64] = sm.ab.A;
    ushort_t (&Bs)[128][64] = sm.ab.B;

    const int t     = threadIdx.x;
    const int wid   = t >> 6;
    const int lane  = t & 63;
    const int lan16 = lane & 15;
    const int quad  = lane >> 4;
    const int wm    = (wid & 1) * 64;
    const int wn    = (wid >> 1) * 64;

    const int col0 = blockIdx.x * 128;
    const int row0 = blockIdx.y * 128;

    // staging: lane l covers row (l>>3), global chunk (l&7)^((l>>3)&7)  (XOR-8 swizzle)
    const int srow = lane >> 3;                       // 0..7
    const int gchk = (lane & 7) ^ ((lane >> 3) & 7);  // swizzled 16B chunk index
    const ushort_t* gA = A + (size_t)(row0 + wid * 8 + srow) * DM + gchk * 8;
    const ushort_t* gB = B + (size_t)(col0 + wid * 8 + srow) * DM + gchk * 8;
    const int lrow = wid * 8 + srow;                  // LDS row within 32-row slab
    const int lchk = (lane & 7) * 8;                  // LDS chunk (ushort offset)

    float4_t acc[4][4];
    #pragma unroll
    for (int i = 0; i < 4; i++)
        #pragma unroll
        for (int j = 0; j < 4; j++) acc[i][j] = (float4_t){0.f, 0.f, 0.f, 0.f};

    const int sw = lan16 & 7;   // fragment-read swizzle key

    // ---- prologue: load + write tile 0
    uint4 ra[4], rb[4];
    #pragma unroll
    for (int j = 0; j < 4; j++) {
        ra[j] = *(const uint4*)(gA + (size_t)j * 32 * DM);
        rb[j] = *(const uint4*)(gB + (size_t)j * 32 * DM);
    }
    #pragma unroll
    for (int j = 0; j < 4; j++) {
        *(uint4*)&As[j * 32 + lrow][lchk] = ra[j];
        *(uint4*)&Bs[j * 32 + lrow][lchk] = rb[j];
    }
    __syncthreads();

    for (int k0 = 0; k0 < DM; k0 += 64) {
        const bool more = (k0 + 64 < DM);
        if (more) {
            #pragma unroll
            for (int j = 0; j < 4; j++) {
                ra[j] = *(const uint4*)(gA + k0 + 64 + (size_t)j * 32 * DM);
                rb[j] = *(const uint4*)(gB + k0 + 64 + (size_t)j * 32 * DM);
            }
        }

        #pragma unroll
        for (int kk = 0; kk < 2; kk++) {
            short8_t af[4], bf[4];
            #pragma unroll
            for (int i = 0; i < 4; i++) {
                af[i] = *(const short8_t*)&As[wm + i * 16 + lan16][((kk * 4 + quad) ^ sw) * 8];
                bf[i] = *(const short8_t*)&Bs[wn + i * 16 + lan16][((kk * 4 + quad) ^ sw) * 8];
            }
            #pragma unroll
            for (int i = 0; i < 4; i++)
                #pragma unroll
                for (int j = 0; j < 4; j++)
                    acc[i][j] = __builtin_amdgcn_mfma_f32_16x16x32_bf16(af[i], bf[j], acc[i][j], 0, 0, 0);
        }

        if (more) {
            __syncthreads();   // fragment readers done with current tile
            #pragma unroll
            for (int j = 0; j < 4; j++) {
                *(uint4*)&As[j * 32 + lrow][lchk] = ra[j];
                *(uint4*)&Bs[j * 32 + lrow][lchk] = rb[j];
            }
            __syncthreads();   // next tile visible
        }
    }

    if (MODE == 1) {
        #pragma unroll
        for (int j = 0; j < 4; j++) {
            int col = col0 + wn + j * 16 + lan16;
            float bv = bias[col];
            #pragma unroll
            for (int i = 0; i < 4; i++) {
                #pragma unroll
                for (int reg = 0; reg < 4; reg++) {
                    int row = row0 + wm + i * 16 + quad * 4 + reg;
                    p_o[(size_t)row * DM + col] = acc[i][j][reg] + bv;
                }
            }
        }
        return;
    }

    // ---- MODE 0 epilogue: LDS-stage + coalesced writeout ----
    const int w = col0 >> 9;   // 0:q 1:k 2:v (uniform per block; 128 | 512)
    __syncthreads();           // all As/Bs readers done before aliasing C over them

    if (w < 2) {
        // straight: C[row][col] (local)
        #pragma unroll
        for (int j = 0; j < 4; j++) {
            float bv = bias[col0 + wn + j * 16 + lan16];
            #pragma unroll
            for (int i = 0; i < 4; i++)
                #pragma unroll
                for (int reg = 0; reg < 4; reg++)
                    sm.C[wm + i * 16 + quad * 4 + reg][wn + j * 16 + lan16] =
                        f2bf(acc[i][j][reg] + bv);
        }
    } else {
        // transposed: C[col][row] (local); pack 4 rows (reg) into one uint2
        #pragma unroll
        for (int j = 0; j < 4; j++) {
            float bv = bias[col0 + wn + j * 16 + lan16];
            #pragma unroll
            for (int i = 0; i < 4; i++) {
                uint2 pw;
                pw.x = cvtpk_bf16(acc[i][j][0] + bv, acc[i][j][1] + bv);
                pw.y = cvtpk_bf16(acc[i][j][2] + bv, acc[i][j][3] + bv);
                *(uint2*)&sm.C[wn + j * 16 + lan16][wm + i * 16 + quad * 4] = pw;
            }
        }
    }
    __syncthreads();

    const int n   = row0 >> 11;
    const int s0  = row0 & 2047;
    const int hh0 = (col0 & 511) >> 6;   // block covers heads hh0, hh0+1

    if (w < 2) {
        ushort_t* dst = (w == 0) ? q_o : k_o;
        #pragma unroll
        for (int it = 0; it < 8; it++) {
            int ch  = it * 256 + t;        // 0..2047
            int s   = ch >> 4;             // local row 0..127
            int c16 = ch & 15;             // 16B chunk within the 128 cols
            int head = hh0 + (c16 >> 3);
            int dq   = (c16 & 7) * 8;
            size_t a = (((size_t)(n * H_N + head)) * SEQ + (s0 + s)) * DH + dq;
            *(uint4*)(dst + a) = *(const uint4*)&sm.C[s][c16 * 8];
        }
    } else {
        #pragma unroll
        for (int it = 0; it < 8; it++) {
            int ch = it * 256 + t;         // 0..2047
            int r  = ch >> 4;              // local col 0..127  (= head*64+dh slice)
            int sg = ch & 15;              // 16B chunk along s
            int head = hh0 + (r >> 6);
            int dh   = r & 63;
            size_t a = (((size_t)(n * H_N + head)) * DH + dh) * SEQ + s0 + sg * 8;
            *(uint4*)(vt_o + a) = *(const uint4*)&sm.C[r][sg * 8];
        }
    }
}

// MFMA flash attention: S^T orientation, no-max softmax.
// Round-15: byte-exact REVERT to the verified round-8 kernel (62.9 us) — the
// round-13/14 Pp time-share couldn't raise occupancy (grid = 512 blocks = 2
// blocks/CU exactly; LDS shrink can't create a 3rd resident block) and its
// extra lgkmcnt serialization cost ~2.5 us.
// Static dual-buffer x2-unrolled K-loop (literal buffer indices -> DS vaddr +
// immediate offsets), j0-based addressing, guarded final prefetch, no setprio.
// S^T = K.Q^T  (C: col=lan16=qrow, row=quad*4+reg=key)
// O^T = V^T.P^T (C: col=lan16=qrow, row=quad*4+reg=dim)
__global__ __launch_bounds__(256)
void attn_k(const ushort_t* __restrict__ qw, const ushort_t* __restrict__ kw,
            const ushort_t* __restrict__ vt, const float* __restrict__ lsc,
            const float* __restrict__ gtab, ushort_t* __restrict__ ctx)
{
    __shared__ __align__(16) ushort_t K_s[2][64][72];       // [buf][key][dim]
    __shared__ __align__(16) ushort_t VT_s[2][64][72];      // [buf][dim][key]
    __shared__ __align__(16) unsigned int Pp[4][2][16][36]; // [wave][qf][qrow16][key-pair]

    const int t     = threadIdx.x;
    const int wid   = t >> 6;     // 0..3
    const int lane  = t & 63;
    const int lan16 = lane & 15;
    const int quad  = lane >> 4;

    const int h  = blockIdx.x;
    const int qt = blockIdx.y;    // 0..15
    const int n  = blockIdx.z;
    const int q0 = qt * 128;

    const size_t headoff = ((size_t)(n * H_N + h)) * SEQ * DH;
    const ushort_t* qh  = qw + headoff;
    const ushort_t* kh  = kw + headoff;
    const ushort_t* vth = vt + headoff;

    float ls = lsc[h];
    const float lm = 4.60517018598809136804f;   // log(100)
    if (ls > lm) ls = lm;
    const float scale2 = __expf(ls) * 0.04419417382415921757f * LOG2E;

    const int qrow0 = q0 + wid * 32 + lan16;    // qf adds +16
    const float4* gt = (const float4*)gtab + (size_t)h * RELN + (qrow0 + 2047 - quad * 4);

    short8_t qb[2][2];
    #pragma unroll
    for (int qf = 0; qf < 2; qf++) {
        const ushort_t* src = qh + (size_t)(qrow0 + qf * 16) * DH + quad * 8;
        qb[qf][0] = *(const short8_t*)(src);
        qb[qf][1] = *(const short8_t*)(src + 32);
    }

    float l_run[2] = {0.f, 0.f};
    float4_t o[4][2];   // [dim-sub][qf]
    #pragma unroll
    for (int ds = 0; ds < 4; ds++)
        #pragma unroll
        for (int qf = 0; qf < 2; qf++) o[ds][qf] = (float4_t){0.f, 0.f, 0.f, 0.f};

    const int srow = t >> 2;        // 0..63
    const int sc   = (t & 3) * 16;  // ushort offset (32B span)
    const ushort_t* kbase = kh + (size_t)srow * DH + sc;
    const ushort_t* vbase = vth + (size_t)srow * SEQ + sc;

    // ---- prologue: stage tile 0 into buf 0, load its bias (even set)
    float4 b4E[2][4];
    {
        uint4 k0r = *(const uint4*)(kbase);
        uint4 k1r = *(const uint4*)(kbase + 8);
        uint4 v0r = *(const uint4*)(vbase);
        uint4 v1r = *(const uint4*)(vbase + 8);
        #pragma unroll
        for (int qf = 0; qf < 2; qf++)
            #pragma unroll
            for (int sub = 0; sub < 4; sub++) b4E[qf][sub] = gt[(qf - sub) * 16];
        *(uint4*)&K_s[0][srow][sc]      = k0r;
        *(uint4*)&K_s[0][srow][sc + 8]  = k1r;
        *(uint4*)&VT_s[0][srow][sc]     = v0r;
        *(uint4*)&VT_s[0][srow][sc + 8] = v1r;
    }
    __syncthreads();

// COMPUTE(B, B4): process current tile from static buffer literal B, bias B4.
#define COMPUTE(B, B4)                                                               \
  {                                                                                  \
    float4_t st[4][2];                                                               \
    _Pragma("unroll")                                                                \
    for (int sub = 0; sub < 4; sub++) {                                              \
        const ushort_t* kp_ = &K_s[B][sub * 16 + lan16][quad * 8];                   \
        short8_t ka0 = *(const short8_t*)(kp_);                                      \
        short8_t ka1 = *(const short8_t*)(kp_ + 32);                                 \
        _Pragma("unroll")                                                            \
        for (int qf = 0; qf < 2; qf++) {                                             \
            float4_t a = (float4_t){0.f, 0.f, 0.f, 0.f};                             \
            a = __builtin_amdgcn_mfma_f32_16x16x32_bf16(ka0, qb[qf][0], a, 0, 0, 0); \
            a = __builtin_amdgcn_mfma_f32_16x16x32_bf16(ka1, qb[qf][1], a, 0, 0, 0); \
            st[sub][qf] = a;                                                         \
        }                                                                            \
    }                                                                                \
    _Pragma("unroll")                                                                \
    for (int qf = 0; qf < 2; qf++) {                                                 \
        float ps = 0.f;                                                              \
        _Pragma("unroll")                                                            \
        for (int sub = 0; sub < 4; sub++) {                                          \
            float e0 = fexp2(st[sub][qf][0] * scale2 + B4[qf][sub].x);               \
            float e1 = fexp2(st[sub][qf][1] * scale2 + B4[qf][sub].y);               \
            float e2 = fexp2(st[sub][qf][2] * scale2 + B4[qf][sub].z);               \
            float e3 = fexp2(st[sub][qf][3] * scale2 + B4[qf][sub].w);               \
            ps += (e0 + e1) + (e2 + e3);                                             \
            uint2 pw;                                                                \
            pw.x = cvtpk_bf16(e0, e1);                                               \
            pw.y = cvtpk_bf16(e2, e3);                                               \
            *(uint2*)&Pp[wid][qf][lan16][sub * 8 + quad * 2] = pw;                   \
        }                                                                            \
        l_run[qf] += ps;                                                             \
    }                                                                                \
    asm volatile("s_waitcnt lgkmcnt(0)" ::: "memory");                               \
    _Pragma("unroll")                                                                \
    for (int ks = 0; ks < 2; ks++) {                                                 \
        short8_t pb[2];                                                              \
        _Pragma("unroll")                                                            \
        for (int qf = 0; qf < 2; qf++)                                               \
            pb[qf] = *(const short8_t*)&Pp[wid][qf][lan16][ks * 16 + quad * 4];      \
        _Pragma("unroll")                                                            \
        for (int ds = 0; ds < 4; ds++) {                                             \
            short8_t va = *(const short8_t*)&VT_s[B][ds * 16 + lan16][ks * 32 + quad * 8]; \
            _Pragma("unroll")                                                        \
            for (int qf = 0; qf < 2; qf++)                                           \
                o[ds][qf] = __builtin_amdgcn_mfma_f32_16x16x32_bf16(va, pb[qf], o[ds][qf], 0, 0, 0); \
        }                                                                            \
    }                                                                                \
  }

    #pragma unroll 1
    for (int it = 0; it < 16; it++) {
        const int j0a = it * 128;          // even tile (buf 0)

        // ---- half A: prefetch tile j0a+64, compute tile j0a from buf 0
        {
            uint4 kr0 = *(const uint4*)(kbase + (size_t)(j0a + 64) * DH);
            uint4 kr1 = *(const uint4*)(kbase + (size_t)(j0a + 64) * DH + 8);
            uint4 vr0 = *(const uint4*)(vbase + (j0a + 64));
            uint4 vr1 = *(const uint4*)(vbase + (j0a + 64) + 8);
            float4 b4O[2][4];
            {
                const float4* gtp = gt - (j0a + 64);
                #pragma unroll
                for (int qf = 0; qf < 2; qf++)
                    #pragma unroll
                    for (int sub = 0; sub < 4; sub++) b4O[qf][sub] = gtp[(qf - sub) * 16];
            }

            COMPUTE(0, b4E);

            *(uint4*)&K_s[1][srow][sc]      = kr0;
            *(uint4*)&K_s[1][srow][sc + 8]  = kr1;
            *(uint4*)&VT_s[1][srow][sc]     = vr0;
            *(uint4*)&VT_s[1][srow][sc + 8] = vr1;
            __syncthreads();

            // ---- half B: prefetch tile j0a+128 (guarded), compute tile j0a+64 from buf 1
            if (it < 15) {
                uint4 ke0 = *(const uint4*)(kbase + (size_t)(j0a + 128) * DH);
                uint4 ke1 = *(const uint4*)(kbase + (size_t)(j0a + 128) * DH + 8);
                uint4 ve0 = *(const uint4*)(vbase + (j0a + 128));
                uint4 ve1 = *(const uint4*)(vbase + (j0a + 128) + 8);
                {
                    const float4* gtp = gt - (j0a + 128);
                    #pragma unroll
                    for (int qf = 0; qf < 2; qf++)
                        #pragma unroll
                        for (int sub = 0; sub < 4; sub++) b4E[qf][sub] = gtp[(qf - sub) * 16];
                }

                COMPUTE(1, b4O);

                *(uint4*)&K_s[0][srow][sc]      = ke0;
                *(uint4*)&K_s[0][srow][sc + 8]  = ke1;
                *(uint4*)&VT_s[0][srow][sc]     = ve0;
                *(uint4*)&VT_s[0][srow][sc + 8] = ve1;
                __syncthreads();
            } else {
                COMPUTE(1, b4O);   // last tile: no prefetch, no write, no barrier
            }
        }
    }
#undef COMPUTE

    // epilogue: reduce l across quads; O^T col=lan16=qrow, row=quad*4+reg=dim; bf16 ctx
    #pragma unroll
    for (int qf = 0; qf < 2; qf++) {
        float l = l_run[qf];
        l += __shfl_xor(l, 16);
        l += __shfl_xor(l, 32);
        float inv = 1.0f / l;
        int row = qrow0 + qf * 16;
        size_t base = ((size_t)n * SEQ + row) * DM + h * DH;
        #pragma unroll
        for (int ds = 0; ds < 4; ds++) {
            uint2 p;
            p.x = cvtpk_bf16(o[ds][qf][0] * inv, o[ds][qf][1] * inv);
            p.y = cvtpk_bf16(o[ds][qf][2] * inv, o[ds][qf][3] * inv);
            *(uint2*)(ctx + base + ds * 16 + quad * 4) = p;
        }
    }
}

extern "C" void kernel_launch(void* const* d_in, const int* in_sizes, int n_in,
                              void* d_out, int out_size, void* d_ws, size_t ws_size,
                              hipStream_t stream) {
    const float* query = (const float*)d_in[0];
    const float* Wq  = (const float*)d_in[1];
    const float* bq  = (const float*)d_in[2];
    const float* Wk  = (const float*)d_in[3];
    const float* bk  = (const float*)d_in[4];
    const float* Wv  = (const float*)d_in[5];
    const float* bv  = (const float*)d_in[6];
    const float* Wp  = (const float*)d_in[7];
    const float* bp  = (const float*)d_in[8];
    const float* lsc = (const float*)d_in[9];
    const float* rpe = (const float*)d_in[10];

    const size_t QEL = (size_t)N_B * SEQ * DM;     // 4,194,304
    const size_t WEL = (size_t)DM * DM;            // 262,144
    char* ws = (char*)d_ws;
    ushort_t* q16  = (ushort_t*)(ws);              // bf16 query
    ushort_t* w16  = q16 + QEL;                    // Wq|Wk|Wv|Wp bf16 (qkv head-major permuted)
    float*    bcat = (float*)(w16 + 4 * WEL);      // 2048 floats (permuted to match)
    float*    gtab = bcat + 2048;                  // 8*4095 float4 = 512 KB
    ushort_t* qb   = (ushort_t*)(gtab + 4 * GTABN);
    ushort_t* kb   = qb + QEL;
    ushort_t* vtb  = kb + QEL;
    ushort_t* ctx  = vtb + QEL;                    // total ~44.5 MB

    const int PREPN = Q4 + 4 * W4 + 2048 + GTABN;
    prep<<<(PREPN + 255) / 256, 256, 0, stream>>>(
        query, Wq, Wk, Wv, Wp, bq, bk, bv, bp, rpe, q16, w16, bcat, gtab);

    dim3 g1(1536 / 128, (N_B * SEQ) / 128);        // (12, 64)
    mgemm<0><<<g1, 256, 0, stream>>>(q16, w16, bcat, qb, kb, vtb, nullptr);

    dim3 ga(H_N, SEQ / 128, N_B);                  // (8, 16, 4): lid%8 == h -> XCD co-residency
    attn_k<<<ga, 256, 0, stream>>>(qb, kb, vtb, lsc, gtab, ctx);

    dim3 g2(DM / 128, (N_B * SEQ) / 128);          // (4, 64)
    mgemm<1><<<g2, 256, 0, stream>>>(ctx, w16 + 3 * WEL, bcat + 1536,
                                     nullptr, nullptr, nullptr, (float*)d_out);
}

// Round 17
// 179.159 us; speedup vs baseline: 1.3071x; 1.3071x over previous
//
#include <hip/hip_runtime.h>
#include <math.h>

#define N_B 4
#define SEQ 2048
#define DM  512
#define H_N 8
#define DH  64

typedef unsigned short ushort_t;
typedef __attribute__((ext_vector_type(8))) short short8_t;
typedef __attribute__((ext_vector_type(4))) float float4_t;

#define LOG2E 1.4426950408889634074f

__device__ __forceinline__ ushort_t f2bf(float f) {
    unsigned int x = __float_as_uint(f);
    unsigned int lsb = (x >> 16) & 1u;
    x += 0x7fffu + lsb;
    return (ushort_t)(x >> 16);
}
__device__ __forceinline__ unsigned int cvtpk_bf16(float a, float b) {
    unsigned int r;
    asm("v_cvt_pk_bf16_f32 %0, %1, %2" : "=v"(r) : "v"(a), "v"(b));
    return r;   // lo = bf16(a), hi = bf16(b), RNE
}
__device__ __forceinline__ float fexp2(float x) {
#if __has_builtin(__builtin_amdgcn_exp2f)
    return __builtin_amdgcn_exp2f(x);
#else
    return exp2f(x);
#endif
}
__device__ __forceinline__ void gload_lds16(const ushort_t* g, ushort_t* l) {
    __builtin_amdgcn_global_load_lds((const __attribute__((address_space(1))) void*)g,
                                     (__attribute__((address_space(3))) void*)l,
                                     16, 0, 0);
}

// Merged pre-pass: query + 4 weights -> bf16 (RNE); bias concat; sigmoid bias table.
// Wq/Wk/Wv output channels PERMUTED head-major: c' = (c&7)*64 + (c>>3), so mgemm<0>
// output col c' decodes hh=c'>>6, dh=c'&63 (coalescable stores). bcat permuted to match.
#define Q4 1048576   // query float4 groups
#define W4 65536     // per-weight float4 groups
#define RELN 4095    // 2*SEQ-1
#define GTABN (H_N * RELN)
__global__ __launch_bounds__(256)
void prep(const float* __restrict__ query,
          const float* __restrict__ Wq, const float* __restrict__ Wk,
          const float* __restrict__ Wv, const float* __restrict__ Wp,
          const float* __restrict__ bq, const float* __restrict__ bk,
          const float* __restrict__ bv, const float* __restrict__ bp,
          const float* __restrict__ rpe,
          ushort_t* __restrict__ q16, ushort_t* __restrict__ w16,
          float* __restrict__ bcat, float* __restrict__ gtab)
{
    int i = blockIdx.x * 256 + threadIdx.x;
    if (i < Q4) {
        float4 x = ((const float4*)query)[i];
        uint2 p;
        p.x = cvtpk_bf16(x.x, x.y);
        p.y = cvtpk_bf16(x.z, x.w);
        ((uint2*)q16)[i] = p;
    } else if (i < Q4 + 4 * W4) {
        int wi = i - Q4;
        int w = wi >> 16;
        const float* W = (w == 0) ? Wq : (w == 1) ? Wk : (w == 2) ? Wv : Wp;
        int gwi = wi & (W4 - 1);
        int c = gwi >> 7;            // original output channel 0..511
        int g = gwi & 127;           // float4 group within row
        float4 x = ((const float4*)W)[gwi];
        uint2 p;
        p.x = cvtpk_bf16(x.x, x.y);
        p.y = cvtpk_bf16(x.z, x.w);
        int c2 = (w < 3) ? (((c & 7) << 6) | (c >> 3)) : c;   // head-major permute
        ((uint2*)w16)[w * W4 + c2 * 128 + g] = p;
    } else if (i < Q4 + 4 * W4 + 2048) {
        int bi = i - (Q4 + 4 * W4);
        int seg = bi >> 9;
        int c = bi & 511;
        const float* B = (seg == 0) ? bq : (seg == 1) ? bk : (seg == 2) ? bv : bp;
        int c2 = (seg < 3) ? (((c & 7) << 6) | (c >> 3)) : c;
        bcat[seg * 512 + c2] = B[c];
    } else {
        int gi = i - (Q4 + 4 * W4 + 2048);
        if (gi < GTABN) {
            int h = gi / RELN;
            int rel = gi - h * RELN;
            float4 v;
            #pragma unroll
            for (int c = 0; c < 4; c++) {
                int rr = rel - c;
                if (rr < 0) rr = 0;                  // components never consumed when rel<3
                float x = rpe[rr * H_N + h];
                ((float*)&v)[c] = LOG2E / (1.0f + __expf(-x));
            }
            ((float4*)gtab)[gi] = v;
        }
    }
}

// Single-pass bf16 MFMA GEMM, round-8-verified code (gload_lds width-16 staging,
// BK=64, XOR-8 chunk swizzle folded into the per-lane GLOBAL read offset; vmcnt(0)
// drain before the staging barrier — replay-race safe, passed tripwires twice).
// Round-17: ONLY change is the blockIdx mapping — row0 = blockIdx.x (64 tiles),
// col0 = blockIdx.y. Linear id = x + 64y, 64 % 8 == 0, so all col-blocks sharing
// an A-row-panel get XCD = x%8 -> same XCD L2 -> each A panel fetched once, not
// col-tiles times (round-15 profile: FETCH 46MB vs ~10MB ideal was this signature).
// C[m,c] = sum_k A[m,k]*W[c,k] + bias[c]
// MODE 0: LDS-staged coalesced epilogue (q/k straight, vt transposed), W head-major.
// MODE 1: fp32 out [m][512] direct.
template<int MODE>
__global__ __launch_bounds__(256)
void mgemm(const ushort_t* __restrict__ A, const ushort_t* __restrict__ B,
           const float* __restrict__ bias,
           ushort_t* __restrict__ q_o, ushort_t* __restrict__ k_o,
           ushort_t* __restrict__ vt_o, float* __restrict__ p_o)
{
    __shared__ __align__(16) union SM {
        struct { ushort_t A[128][64]; ushort_t B[128][64]; } ab;   // 32 KB staging
        ushort_t C[128][128];                                      // 32 KB epilogue tile
    } sm;
    ushort_t (&As)[128][64] = sm.ab.A;
    ushort_t (&Bs)[128][64] = sm.ab.B;

    const int t     = threadIdx.x;
    const int wid   = t >> 6;
    const int lane  = t & 63;
    const int lan16 = lane & 15;
    const int quad  = lane >> 4;
    const int wm    = (wid & 1) * 64;
    const int wn    = (wid >> 1) * 64;

    const int row0 = blockIdx.x * 128;   // swapped: rows on x for XCD co-location
    const int col0 = blockIdx.y * 128;

    // staging: lane l covers row (l>>3), global chunk (l&7)^((l>>3)&7)  (XOR-8 swizzle)
    const int srow = lane >> 3;                       // 0..7
    const int gchk = (lane & 7) ^ ((lane >> 3) & 7);  // swizzled 16B chunk index
    const ushort_t* gA = A + (size_t)(row0 + wid * 8 + srow) * DM + gchk * 8;
    const ushort_t* gB = B + (size_t)(col0 + wid * 8 + srow) * DM + gchk * 8;

    float4_t acc[4][4];
    #pragma unroll
    for (int i = 0; i < 4; i++)
        #pragma unroll
        for (int j = 0; j < 4; j++) acc[i][j] = (float4_t){0.f, 0.f, 0.f, 0.f};

    const int sw = lan16 & 7;   // fragment-read swizzle key

    for (int k0 = 0; k0 < DM; k0 += 64) {
        __syncthreads();   // prev-iter fragment readers done
        #pragma unroll
        for (int j = 0; j < 4; j++) {
            gload_lds16(gA + k0 + (size_t)j * 32 * DM, &As[j * 32 + wid * 8][0]);
            gload_lds16(gB + k0 + (size_t)j * 32 * DM, &Bs[j * 32 + wid * 8][0]);
        }
        asm volatile("s_waitcnt vmcnt(0)" ::: "memory");  // drain async DMA before barrier
        __syncthreads();   // staging complete

        #pragma unroll
        for (int kk = 0; kk < 2; kk++) {
            short8_t af[4], bf[4];
            #pragma unroll
            for (int i = 0; i < 4; i++) {
                af[i] = *(const short8_t*)&As[wm + i * 16 + lan16][((kk * 4 + quad) ^ sw) * 8];
                bf[i] = *(const short8_t*)&Bs[wn + i * 16 + lan16][((kk * 4 + quad) ^ sw) * 8];
            }
            #pragma unroll
            for (int i = 0; i < 4; i++)
                #pragma unroll
                for (int j = 0; j < 4; j++)
                    acc[i][j] = __builtin_amdgcn_mfma_f32_16x16x32_bf16(af[i], bf[j], acc[i][j], 0, 0, 0);
        }
    }

    if (MODE == 1) {
        #pragma unroll
        for (int j = 0; j < 4; j++) {
            int col = col0 + wn + j * 16 + lan16;
            float bv = bias[col];
            #pragma unroll
            for (int i = 0; i < 4; i++) {
                #pragma unroll
                for (int reg = 0; reg < 4; reg++) {
                    int row = row0 + wm + i * 16 + quad * 4 + reg;
                    p_o[(size_t)row * DM + col] = acc[i][j][reg] + bv;
                }
            }
        }
        return;
    }

    // ---- MODE 0 epilogue: LDS-stage + coalesced writeout ----
    const int w = col0 >> 9;   // 0:q 1:k 2:v (uniform per block; 128 | 512)
    __syncthreads();           // all As/Bs readers done before aliasing C over them

    if (w < 2) {
        // straight: C[row][col] (local)
        #pragma unroll
        for (int j = 0; j < 4; j++) {
            float bv = bias[col0 + wn + j * 16 + lan16];
            #pragma unroll
            for (int i = 0; i < 4; i++)
                #pragma unroll
                for (int reg = 0; reg < 4; reg++)
                    sm.C[wm + i * 16 + quad * 4 + reg][wn + j * 16 + lan16] =
                        f2bf(acc[i][j][reg] + bv);
        }
    } else {
        // transposed: C[col][row] (local); pack 4 rows (reg) into one uint2
        #pragma unroll
        for (int j = 0; j < 4; j++) {
            float bv = bias[col0 + wn + j * 16 + lan16];
            #pragma unroll
            for (int i = 0; i < 4; i++) {
                uint2 pw;
                pw.x = cvtpk_bf16(acc[i][j][0] + bv, acc[i][j][1] + bv);
                pw.y = cvtpk_bf16(acc[i][j][2] + bv, acc[i][j][3] + bv);
                *(uint2*)&sm.C[wn + j * 16 + lan16][wm + i * 16 + quad * 4] = pw;
            }
        }
    }
    __syncthreads();

    const int n   = row0 >> 11;
    const int s0  = row0 & 2047;
    const int hh0 = (col0 & 511) >> 6;   // block covers heads hh0, hh0+1

    if (w < 2) {
        ushort_t* dst = (w == 0) ? q_o : k_o;
        #pragma unroll
        for (int it = 0; it < 8; it++) {
            int ch  = it * 256 + t;        // 0..2047
            int s   = ch >> 4;             // local row 0..127
            int c16 = ch & 15;             // 16B chunk within the 128 cols
            int head = hh0 + (c16 >> 3);
            int dq   = (c16 & 7) * 8;
            size_t a = (((size_t)(n * H_N + head)) * SEQ + (s0 + s)) * DH + dq;
            *(uint4*)(dst + a) = *(const uint4*)&sm.C[s][c16 * 8];
        }
    } else {
        #pragma unroll
        for (int it = 0; it < 8; it++) {
            int ch = it * 256 + t;         // 0..2047
            int r  = ch >> 4;              // local col 0..127  (= head*64+dh slice)
            int sg = ch & 15;              // 16B chunk along s
            int head = hh0 + (r >> 6);
            int dh   = r & 63;
            size_t a = (((size_t)(n * H_N + head)) * DH + dh) * SEQ + s0 + sg * 8;
            *(uint4*)(vt_o + a) = *(const uint4*)&sm.C[r][sg * 8];
        }
    }
}

// MFMA flash attention: S^T orientation, no-max softmax. Round-8 VERBATIM
// (verified best, 62.9 us, replay-tripwire-clean): static dual-buffer
// x2-unrolled K-loop (literal buffer indices -> DS vaddr + immediate offsets),
// j0-based addressing, guarded final prefetch, no setprio.
// S^T = K.Q^T  (C: col=lan16=qrow, row=quad*4+reg=key)
// O^T = V^T.P^T (C: col=lan16=qrow, row=quad*4+reg=dim)
__global__ __launch_bounds__(256)
void attn_k(const ushort_t* __restrict__ qw, const ushort_t* __restrict__ kw,
            const ushort_t* __restrict__ vt, const float* __restrict__ lsc,
            const float* __restrict__ gtab, ushort_t* __restrict__ ctx)
{
    __shared__ __align__(16) ushort_t K_s[2][64][72];       // [buf][key][dim]
    __shared__ __align__(16) ushort_t VT_s[2][64][72];      // [buf][dim][key]
    __shared__ __align__(16) unsigned int Pp[4][2][16][36]; // [wave][qf][qrow16][key-pair]

    const int t     = threadIdx.x;
    const int wid   = t >> 6;     // 0..3
    const int lane  = t & 63;
    const int lan16 = lane & 15;
    const int quad  = lane >> 4;

    const int h  = blockIdx.x;
    const int qt = blockIdx.y;    // 0..15
    const int n  = blockIdx.z;
    const int q0 = qt * 128;

    const size_t headoff = ((size_t)(n * H_N + h)) * SEQ * DH;
    const ushort_t* qh  = qw + headoff;
    const ushort_t* kh  = kw + headoff;
    const ushort_t* vth = vt + headoff;

    float ls = lsc[h];
    const float lm = 4.60517018598809136804f;   // log(100)
    if (ls > lm) ls = lm;
    const float scale2 = __expf(ls) * 0.04419417382415921757f * LOG2E;

    const int qrow0 = q0 + wid * 32 + lan16;    // qf adds +16
    const float4* gt = (const float4*)gtab + (size_t)h * RELN + (qrow0 + 2047 - quad * 4);

    short8_t qb[2][2];
    #pragma unroll
    for (int qf = 0; qf < 2; qf++) {
        const ushort_t* src = qh + (size_t)(qrow0 + qf * 16) * DH + quad * 8;
        qb[qf][0] = *(const short8_t*)(src);
        qb[qf][1] = *(const short8_t*)(src + 32);
    }

    float l_run[2] = {0.f, 0.f};
    float4_t o[4][2];   // [dim-sub][qf]
    #pragma unroll
    for (int ds = 0; ds < 4; ds++)
        #pragma unroll
        for (int qf = 0; qf < 2; qf++) o[ds][qf] = (float4_t){0.f, 0.f, 0.f, 0.f};

    const int srow = t >> 2;        // 0..63
    const int sc   = (t & 3) * 16;  // ushort offset (32B span)
    const ushort_t* kbase = kh + (size_t)srow * DH + sc;
    const ushort_t* vbase = vth + (size_t)srow * SEQ + sc;

    // ---- prologue: stage tile 0 into buf 0, load its bias (even set)
    float4 b4E[2][4];
    {
        uint4 k0r = *(const uint4*)(kbase);
        uint4 k1r = *(const uint4*)(kbase + 8);
        uint4 v0r = *(const uint4*)(vbase);
        uint4 v1r = *(const uint4*)(vbase + 8);
        #pragma unroll
        for (int qf = 0; qf < 2; qf++)
            #pragma unroll
            for (int sub = 0; sub < 4; sub++) b4E[qf][sub] = gt[(qf - sub) * 16];
        *(uint4*)&K_s[0][srow][sc]      = k0r;
        *(uint4*)&K_s[0][srow][sc + 8]  = k1r;
        *(uint4*)&VT_s[0][srow][sc]     = v0r;
        *(uint4*)&VT_s[0][srow][sc + 8] = v1r;
    }
    __syncthreads();

// COMPUTE(B, B4): process current tile from static buffer literal B, bias B4.
#define COMPUTE(B, B4)                                                               \
  {                                                                                  \
    float4_t st[4][2];                                                               \
    _Pragma("unroll")                                                                \
    for (int sub = 0; sub < 4; sub++) {                                              \
        const ushort_t* kp_ = &K_s[B][sub * 16 + lan16][quad * 8];                   \
        short8_t ka0 = *(const short8_t*)(kp_);                                      \
        short8_t ka1 = *(const short8_t*)(kp_ + 32);                                 \
        _Pragma("unroll")                                                            \
        for (int qf = 0; qf < 2; qf++) {                                             \
            float4_t a = (float4_t){0.f, 0.f, 0.f, 0.f};                             \
            a = __builtin_amdgcn_mfma_f32_16x16x32_bf16(ka0, qb[qf][0], a, 0, 0, 0); \
            a = __builtin_amdgcn_mfma_f32_16x16x32_bf16(ka1, qb[qf][1], a, 0, 0, 0); \
            st[sub][qf] = a;                                                         \
        }                                                                            \
    }                                                                                \
    _Pragma("unroll")                                                                \
    for (int qf = 0; qf < 2; qf++) {                                                 \
        float ps = 0.f;                                                              \
        _Pragma("unroll")                                                            \
        for (int sub = 0; sub < 4; sub++) {                                          \
            float e0 = fexp2(st[sub][qf][0] * scale2 + B4[qf][sub].x);               \
            float e1 = fexp2(st[sub][qf][1] * scale2 + B4[qf][sub].y);               \
            float e2 = fexp2(st[sub][qf][2] * scale2 + B4[qf][sub].z);               \
            float e3 = fexp2(st[sub][qf][3] * scale2 + B4[qf][sub].w);               \
            ps += (e0 + e1) + (e2 + e3);                                             \
            uint2 pw;                                                                \
            pw.x = cvtpk_bf16(e0, e1);                                               \
            pw.y = cvtpk_bf16(e2, e3);                                               \
            *(uint2*)&Pp[wid][qf][lan16][sub * 8 + quad * 2] = pw;                   \
        }                                                                            \
        l_run[qf] += ps;                                                             \
    }                                                                                \
    asm volatile("s_waitcnt lgkmcnt(0)" ::: "memory");                               \
    _Pragma("unroll")                                                                \
    for (int ks = 0; ks < 2; ks++) {                                                 \
        short8_t pb[2];                                                              \
        _Pragma("unroll")                                                            \
        for (int qf = 0; qf < 2; qf++)                                               \
            pb[qf] = *(const short8_t*)&Pp[wid][qf][lan16][ks * 16 + quad * 4];      \
        _Pragma("unroll")                                                            \
        for (int ds = 0; ds < 4; ds++) {                                             \
            short8_t va = *(const short8_t*)&VT_s[B][ds * 16 + lan16][ks * 32 + quad * 8]; \
            _Pragma("unroll")                                                        \
            for (int qf = 0; qf < 2; qf++)                                           \
                o[ds][qf] = __builtin_amdgcn_mfma_f32_16x16x32_bf16(va, pb[qf], o[ds][qf], 0, 0, 0); \
        }                                                                            \
    }                                                                                \
  }

    #pragma unroll 1
    for (int it = 0; it < 16; it++) {
        const int j0a = it * 128;          // even tile (buf 0)

        // ---- half A: prefetch tile j0a+64, compute tile j0a from buf 0
        {
            uint4 kr0 = *(const uint4*)(kbase + (size_t)(j0a + 64) * DH);
            uint4 kr1 = *(const uint4*)(kbase + (size_t)(j0a + 64) * DH + 8);
            uint4 vr0 = *(const uint4*)(vbase + (j0a + 64));
            uint4 vr1 = *(const uint4*)(vbase + (j0a + 64) + 8);
            float4 b4O[2][4];
            {
                const float4* gtp = gt - (j0a + 64);
                #pragma unroll
                for (int qf = 0; qf < 2; qf++)
                    #pragma unroll
                    for (int sub = 0; sub < 4; sub++) b4O[qf][sub] = gtp[(qf - sub) * 16];
            }

            COMPUTE(0, b4E);

            *(uint4*)&K_s[1][srow][sc]      = kr0;
            *(uint4*)&K_s[1][srow][sc + 8]  = kr1;
            *(uint4*)&VT_s[1][srow][sc]     = vr0;
            *(uint4*)&VT_s[1][srow][sc + 8] = vr1;
            __syncthreads();

            // ---- half B: prefetch tile j0a+128 (guarded), compute tile j0a+64 from buf 1
            if (it < 15) {
                uint4 ke0 = *(const uint4*)(kbase + (size_t)(j0a + 128) * DH);
                uint4 ke1 = *(const uint4*)(kbase + (size_t)(j0a + 128) * DH + 8);
                uint4 ve0 = *(const uint4*)(vbase + (j0a + 128));
                uint4 ve1 = *(const uint4*)(vbase + (j0a + 128) + 8);
                {
                    const float4* gtp = gt - (j0a + 128);
                    #pragma unroll
                    for (int qf = 0; qf < 2; qf++)
                        #pragma unroll
                        for (int sub = 0; sub < 4; sub++) b4E[qf][sub] = gtp[(qf - sub) * 16];
                }

                COMPUTE(1, b4O);

                *(uint4*)&K_s[0][srow][sc]      = ke0;
                *(uint4*)&K_s[0][srow][sc + 8]  = ke1;
                *(uint4*)&VT_s[0][srow][sc]     = ve0;
                *(uint4*)&VT_s[0][srow][sc + 8] = ve1;
                __syncthreads();
            } else {
                COMPUTE(1, b4O);   // last tile: no prefetch, no write, no barrier
            }
        }
    }
#undef COMPUTE

    // epilogue: reduce l across quads; O^T col=lan16=qrow, row=quad*4+reg=dim; bf16 ctx
    #pragma unroll
    for (int qf = 0; qf < 2; qf++) {
        float l = l_run[qf];
        l += __shfl_xor(l, 16);
        l += __shfl_xor(l, 32);
        float inv = 1.0f / l;
        int row = qrow0 + qf * 16;
        size_t base = ((size_t)n * SEQ + row) * DM + h * DH;
        #pragma unroll
        for (int ds = 0; ds < 4; ds++) {
            uint2 p;
            p.x = cvtpk_bf16(o[ds][qf][0] * inv, o[ds][qf][1] * inv);
            p.y = cvtpk_bf16(o[ds][qf][2] * inv, o[ds][qf][3] * inv);
            *(uint2*)(ctx + base + ds * 16 + quad * 4) = p;
        }
    }
}

extern "C" void kernel_launch(void* const* d_in, const int* in_sizes, int n_in,
                              void* d_out, int out_size, void* d_ws, size_t ws_size,
                              hipStream_t stream) {
    const float* query = (const float*)d_in[0];
    const float* Wq  = (const float*)d_in[1];
    const float* bq  = (const float*)d_in[2];
    const float* Wk  = (const float*)d_in[3];
    const float* bk  = (const float*)d_in[4];
    const float* Wv  = (const float*)d_in[5];
    const float* bv  = (const float*)d_in[6];
    const float* Wp  = (const float*)d_in[7];
    const float* bp  = (const float*)d_in[8];
    const float* lsc = (const float*)d_in[9];
    const float* rpe = (const float*)d_in[10];

    const size_t QEL = (size_t)N_B * SEQ * DM;     // 4,194,304
    const size_t WEL = (size_t)DM * DM;            // 262,144
    char* ws = (char*)d_ws;
    ushort_t* q16  = (ushort_t*)(ws);              // bf16 query
    ushort_t* w16  = q16 + QEL;                    // Wq|Wk|Wv|Wp bf16 (qkv head-major permuted)
    float*    bcat = (float*)(w16 + 4 * WEL);      // 2048 floats (permuted to match)
    float*    gtab = bcat + 2048;                  // 8*4095 float4 = 512 KB
    ushort_t* qb   = (ushort_t*)(gtab + 4 * GTABN);
    ushort_t* kb   = qb + QEL;
    ushort_t* vtb  = kb + QEL;
    ushort_t* ctx  = vtb + QEL;                    // total ~44.5 MB

    const int PREPN = Q4 + 4 * W4 + 2048 + GTABN;
    prep<<<(PREPN + 255) / 256, 256, 0, stream>>>(
        query, Wq, Wk, Wv, Wp, bq, bk, bv, bp, rpe, q16, w16, bcat, gtab);

    dim3 g1((N_B * SEQ) / 128, 1536 / 128);        // (64, 12): rows on x -> A panels XCD-pinned
    mgemm<0><<<g1, 256, 0, stream>>>(q16, w16, bcat, qb, kb, vtb, nullptr);

    dim3 ga(H_N, SEQ / 128, N_B);                  // (8, 16, 4): lid%8 == h -> XCD co-residency
    attn_k<<<ga, 256, 0, stream>>>(qb, kb, vtb, lsc, gtab, ctx);

    dim3 g2((N_B * SEQ) / 128, DM / 128);          // (64, 4): rows on x
    mgemm<1><<<g2, 256, 0, stream>>>(ctx, w16 + 3 * WEL, bcat + 1536,
                                     nullptr, nullptr, nullptr, (float*)d_out);
}

// Round 18
// 176.805 us; speedup vs baseline: 1.3245x; 1.0133x over previous
//
#include <hip/hip_runtime.h>
#include <math.h>

#define N_B 4
#define SEQ 2048
#define DM  512
#define H_N 8
#define DH  64

typedef unsigned short ushort_t;
typedef __attribute__((ext_vector_type(8))) short short8_t;
typedef __attribute__((ext_vector_type(4))) float float4_t;

#define LOG2E 1.4426950408889634074f

__device__ __forceinline__ ushort_t f2bf(float f) {
    unsigned int x = __float_as_uint(f);
    unsigned int lsb = (x >> 16) & 1u;
    x += 0x7fffu + lsb;
    return (ushort_t)(x >> 16);
}
__device__ __forceinline__ unsigned int cvtpk_bf16(float a, float b) {
    unsigned int r;
    asm("v_cvt_pk_bf16_f32 %0, %1, %2" : "=v"(r) : "v"(a), "v"(b));
    return r;   // lo = bf16(a), hi = bf16(b), RNE
}
__device__ __forceinline__ float fexp2(float x) {
#if __has_builtin(__builtin_amdgcn_exp2f)
    return __builtin_amdgcn_exp2f(x);
#else
    return exp2f(x);
#endif
}
__device__ __forceinline__ void gload_lds16(const ushort_t* g, ushort_t* l) {
    __builtin_amdgcn_global_load_lds((const __attribute__((address_space(1))) void*)g,
                                     (__attribute__((address_space(3))) void*)l,
                                     16, 0, 0);
}

// Merged pre-pass: query + 4 weights -> bf16 (RNE); bias concat; sigmoid bias table.
// Wq/Wk/Wv output channels PERMUTED head-major: c' = (c&7)*64 + (c>>3), so mgemm<0>
// output col c' decodes hh=c'>>6, dh=c'&63 (coalescable stores). bcat permuted to match.
#define Q4 1048576   // query float4 groups
#define W4 65536     // per-weight float4 groups
#define RELN 4095    // 2*SEQ-1
#define GTABN (H_N * RELN)
__global__ __launch_bounds__(256)
void prep(const float* __restrict__ query,
          const float* __restrict__ Wq, const float* __restrict__ Wk,
          const float* __restrict__ Wv, const float* __restrict__ Wp,
          const float* __restrict__ bq, const float* __restrict__ bk,
          const float* __restrict__ bv, const float* __restrict__ bp,
          const float* __restrict__ rpe,
          ushort_t* __restrict__ q16, ushort_t* __restrict__ w16,
          float* __restrict__ bcat, float* __restrict__ gtab)
{
    int i = blockIdx.x * 256 + threadIdx.x;
    if (i < Q4) {
        float4 x = ((const float4*)query)[i];
        uint2 p;
        p.x = cvtpk_bf16(x.x, x.y);
        p.y = cvtpk_bf16(x.z, x.w);
        ((uint2*)q16)[i] = p;
    } else if (i < Q4 + 4 * W4) {
        int wi = i - Q4;
        int w = wi >> 16;
        const float* W = (w == 0) ? Wq : (w == 1) ? Wk : (w == 2) ? Wv : Wp;
        int gwi = wi & (W4 - 1);
        int c = gwi >> 7;            // original output channel 0..511
        int g = gwi & 127;           // float4 group within row
        float4 x = ((const float4*)W)[gwi];
        uint2 p;
        p.x = cvtpk_bf16(x.x, x.y);
        p.y = cvtpk_bf16(x.z, x.w);
        int c2 = (w < 3) ? (((c & 7) << 6) | (c >> 3)) : c;   // head-major permute
        ((uint2*)w16)[w * W4 + c2 * 128 + g] = p;
    } else if (i < Q4 + 4 * W4 + 2048) {
        int bi = i - (Q4 + 4 * W4);
        int seg = bi >> 9;
        int c = bi & 511;
        const float* B = (seg == 0) ? bq : (seg == 1) ? bk : (seg == 2) ? bv : bp;
        int c2 = (seg < 3) ? (((c & 7) << 6) | (c >> 3)) : c;
        bcat[seg * 512 + c2] = B[c];
    } else {
        int gi = i - (Q4 + 4 * W4 + 2048);
        if (gi < GTABN) {
            int h = gi / RELN;
            int rel = gi - h * RELN;
            float4 v;
            #pragma unroll
            for (int c = 0; c < 4; c++) {
                int rr = rel - c;
                if (rr < 0) rr = 0;                  // components never consumed when rel<3
                float x = rpe[rr * H_N + h];
                ((float*)&v)[c] = LOG2E / (1.0f + __expf(-x));
            }
            ((float4*)gtab)[gi] = v;
        }
    }
}

// Single-pass bf16 MFMA GEMM, round-8-verified code (gload_lds width-16 staging,
// BK=64, XOR-8 chunk swizzle folded into the per-lane GLOBAL read offset; vmcnt(0)
// drain before the staging barrier). Grid mapping: row0 = blockIdx.x (64 tiles),
// col0 = blockIdx.y — linear id = x + 64y, 64 % 8 == 0 -> col-blocks sharing an
// A-row-panel are XCD-pinned (replay-verified in round 17).
// C[m,c] = sum_k A[m,k]*W[c,k] + bias[c]
// MODE 0: LDS-staged coalesced epilogue (q/k straight, vt transposed), W head-major.
// MODE 1: fp32 out [m][512] direct (unused since round 18; kept for fallback).
template<int MODE>
__global__ __launch_bounds__(256)
void mgemm(const ushort_t* __restrict__ A, const ushort_t* __restrict__ B,
           const float* __restrict__ bias,
           ushort_t* __restrict__ q_o, ushort_t* __restrict__ k_o,
           ushort_t* __restrict__ vt_o, float* __restrict__ p_o)
{
    __shared__ __align__(16) union SM {
        struct { ushort_t A[128][64]; ushort_t B[128][64]; } ab;   // 32 KB staging
        ushort_t C[128][128];                                      // 32 KB epilogue tile
    } sm;
    ushort_t (&As)[128][64] = sm.ab.A;
    ushort_t (&Bs)[128][64] = sm.ab.B;

    const int t     = threadIdx.x;
    const int wid   = t >> 6;
    const int lane  = t & 63;
    const int lan16 = lane & 15;
    const int quad  = lane >> 4;
    const int wm    = (wid & 1) * 64;
    const int wn    = (wid >> 1) * 64;

    const int row0 = blockIdx.x * 128;   // rows on x for XCD co-location
    const int col0 = blockIdx.y * 128;

    // staging: lane l covers row (l>>3), global chunk (l&7)^((l>>3)&7)  (XOR-8 swizzle)
    const int srow = lane >> 3;                       // 0..7
    const int gchk = (lane & 7) ^ ((lane >> 3) & 7);  // swizzled 16B chunk index
    const ushort_t* gA = A + (size_t)(row0 + wid * 8 + srow) * DM + gchk * 8;
    const ushort_t* gB = B + (size_t)(col0 + wid * 8 + srow) * DM + gchk * 8;

    float4_t acc[4][4];
    #pragma unroll
    for (int i = 0; i < 4; i++)
        #pragma unroll
        for (int j = 0; j < 4; j++) acc[i][j] = (float4_t){0.f, 0.f, 0.f, 0.f};

    const int sw = lan16 & 7;   // fragment-read swizzle key

    for (int k0 = 0; k0 < DM; k0 += 64) {
        __syncthreads();   // prev-iter fragment readers done
        #pragma unroll
        for (int j = 0; j < 4; j++) {
            gload_lds16(gA + k0 + (size_t)j * 32 * DM, &As[j * 32 + wid * 8][0]);
            gload_lds16(gB + k0 + (size_t)j * 32 * DM, &Bs[j * 32 + wid * 8][0]);
        }
        asm volatile("s_waitcnt vmcnt(0)" ::: "memory");  // drain async DMA before barrier
        __syncthreads();   // staging complete

        #pragma unroll
        for (int kk = 0; kk < 2; kk++) {
            short8_t af[4], bf[4];
            #pragma unroll
            for (int i = 0; i < 4; i++) {
                af[i] = *(const short8_t*)&As[wm + i * 16 + lan16][((kk * 4 + quad) ^ sw) * 8];
                bf[i] = *(const short8_t*)&Bs[wn + i * 16 + lan16][((kk * 4 + quad) ^ sw) * 8];
            }
            #pragma unroll
            for (int i = 0; i < 4; i++)
                #pragma unroll
                for (int j = 0; j < 4; j++)
                    acc[i][j] = __builtin_amdgcn_mfma_f32_16x16x32_bf16(af[i], bf[j], acc[i][j], 0, 0, 0);
        }
    }

    if (MODE == 1) {
        #pragma unroll
        for (int j = 0; j < 4; j++) {
            int col = col0 + wn + j * 16 + lan16;
            float bv = bias[col];
            #pragma unroll
            for (int i = 0; i < 4; i++) {
                #pragma unroll
                for (int reg = 0; reg < 4; reg++) {
                    int row = row0 + wm + i * 16 + quad * 4 + reg;
                    p_o[(size_t)row * DM + col] = acc[i][j][reg] + bv;
                }
            }
        }
        return;
    }

    // ---- MODE 0 epilogue: LDS-stage + coalesced writeout ----
    const int w = col0 >> 9;   // 0:q 1:k 2:v (uniform per block; 128 | 512)
    __syncthreads();           // all As/Bs readers done before aliasing C over them

    if (w < 2) {
        // straight: C[row][col] (local)
        #pragma unroll
        for (int j = 0; j < 4; j++) {
            float bv = bias[col0 + wn + j * 16 + lan16];
            #pragma unroll
            for (int i = 0; i < 4; i++)
                #pragma unroll
                for (int reg = 0; reg < 4; reg++)
                    sm.C[wm + i * 16 + quad * 4 + reg][wn + j * 16 + lan16] =
                        f2bf(acc[i][j][reg] + bv);
        }
    } else {
        // transposed: C[col][row] (local); pack 4 rows (reg) into one uint2
        #pragma unroll
        for (int j = 0; j < 4; j++) {
            float bv = bias[col0 + wn + j * 16 + lan16];
            #pragma unroll
            for (int i = 0; i < 4; i++) {
                uint2 pw;
                pw.x = cvtpk_bf16(acc[i][j][0] + bv, acc[i][j][1] + bv);
                pw.y = cvtpk_bf16(acc[i][j][2] + bv, acc[i][j][3] + bv);
                *(uint2*)&sm.C[wn + j * 16 + lan16][wm + i * 16 + quad * 4] = pw;
            }
        }
    }
    __syncthreads();

    const int n   = row0 >> 11;
    const int s0  = row0 & 2047;
    const int hh0 = (col0 & 511) >> 6;   // block covers heads hh0, hh0+1

    if (w < 2) {
        ushort_t* dst = (w == 0) ? q_o : k_o;
        #pragma unroll
        for (int it = 0; it < 8; it++) {
            int ch  = it * 256 + t;        // 0..2047
            int s   = ch >> 4;             // local row 0..127
            int c16 = ch & 15;             // 16B chunk within the 128 cols
            int head = hh0 + (c16 >> 3);
            int dq   = (c16 & 7) * 8;
            size_t a = (((size_t)(n * H_N + head)) * SEQ + (s0 + s)) * DH + dq;
            *(uint4*)(dst + a) = *(const uint4*)&sm.C[s][c16 * 8];
        }
    } else {
        #pragma unroll
        for (int it = 0; it < 8; it++) {
            int ch = it * 256 + t;         // 0..2047
            int r  = ch >> 4;              // local col 0..127  (= head*64+dh slice)
            int sg = ch & 15;              // 16B chunk along s
            int head = hh0 + (r >> 6);
            int dh   = r & 63;
            size_t a = (((size_t)(n * H_N + head)) * DH + dh) * SEQ + s0 + sg * 8;
            *(uint4*)(vt_o + a) = *(const uint4*)&sm.C[r][sg * 8];
        }
    }
}

// Output-projection GEMM. Round-18: single new kernel vs the replay-verified
// round-17 build. 128x64 tile, grid (64, 8) = 512 blocks = 2 blocks/CU =
// 8 waves/CU (replaces mgemm<1>'s 256 blocks = 1 wave/SIMD, latency-naked,
// ~40us for work with a ~10us floor). Staging audit: As 4x gload_lds covers
// rows 0..127 each-once; Bs 2x gload_lds covers rows 0..63 each-once; LDS
// dests wave-uniform; source XOR-8 swizzle matches the ^sw fragment-read
// algebra (LDS[row][c] holds global chunk c^(row&7), read at (kk*4+quad)^sw
// with sw=lan16&7 = row&7 — identical invariant to the verified template);
// vmcnt(0) drain before the staging barrier; uniform 6 DMA issues per wave;
// no union aliasing; direct fp32 epilogue.
__global__ __launch_bounds__(256)
void mgemm1_k(const ushort_t* __restrict__ A, const ushort_t* __restrict__ B,
              const float* __restrict__ bias, float* __restrict__ p_o)
{
    __shared__ __align__(16) ushort_t As[128][64];   // 16 KB
    __shared__ __align__(16) ushort_t Bs[64][64];    // 8 KB

    const int t     = threadIdx.x;
    const int wid   = t >> 6;
    const int lane  = t & 63;
    const int lan16 = lane & 15;
    const int quad  = lane >> 4;
    const int wm    = (wid & 1) * 64;    // 2-way row split
    const int wn    = (wid >> 1) * 32;   // 2-way col split

    const int row0 = blockIdx.x * 128;   // 64 tiles
    const int col0 = blockIdx.y * 64;    // 8 tiles

    const int srow = lane >> 3;                       // 0..7
    const int gchk = (lane & 7) ^ ((lane >> 3) & 7);  // swizzled 16B chunk index
    const ushort_t* gA = A + (size_t)(row0 + wid * 8 + srow) * DM + gchk * 8;
    const ushort_t* gB = B + (size_t)(col0 + wid * 8 + srow) * DM + gchk * 8;

    float4_t acc[4][2];
    #pragma unroll
    for (int i = 0; i < 4; i++)
        #pragma unroll
        for (int j = 0; j < 2; j++) acc[i][j] = (float4_t){0.f, 0.f, 0.f, 0.f};

    const int sw = lan16 & 7;

    for (int k0 = 0; k0 < DM; k0 += 64) {
        __syncthreads();
        #pragma unroll
        for (int j = 0; j < 4; j++)
            gload_lds16(gA + k0 + (size_t)j * 32 * DM, &As[j * 32 + wid * 8][0]);
        #pragma unroll
        for (int j = 0; j < 2; j++)
            gload_lds16(gB + k0 + (size_t)j * 32 * DM, &Bs[j * 32 + wid * 8][0]);
        asm volatile("s_waitcnt vmcnt(0)" ::: "memory");
        __syncthreads();

        #pragma unroll
        for (int kk = 0; kk < 2; kk++) {
            short8_t af[4], bf[2];
            #pragma unroll
            for (int i = 0; i < 4; i++)
                af[i] = *(const short8_t*)&As[wm + i * 16 + lan16][((kk * 4 + quad) ^ sw) * 8];
            #pragma unroll
            for (int j = 0; j < 2; j++)
                bf[j] = *(const short8_t*)&Bs[wn + j * 16 + lan16][((kk * 4 + quad) ^ sw) * 8];
            #pragma unroll
            for (int i = 0; i < 4; i++)
                #pragma unroll
                for (int j = 0; j < 2; j++)
                    acc[i][j] = __builtin_amdgcn_mfma_f32_16x16x32_bf16(af[i], bf[j], acc[i][j], 0, 0, 0);
        }
    }

    #pragma unroll
    for (int j = 0; j < 2; j++) {
        int col = col0 + wn + j * 16 + lan16;
        float bv = bias[col];
        #pragma unroll
        for (int i = 0; i < 4; i++) {
            #pragma unroll
            for (int reg = 0; reg < 4; reg++) {
                int row = row0 + wm + i * 16 + quad * 4 + reg;
                p_o[(size_t)row * DM + col] = acc[i][j][reg] + bv;
            }
        }
    }
}

// MFMA flash attention: S^T orientation, no-max softmax. Round-8 VERBATIM
// (verified best, replay-tripwire-clean): static dual-buffer x2-unrolled K-loop
// (literal buffer indices -> DS vaddr + immediate offsets), j0-based addressing,
// guarded final prefetch, no setprio.
// S^T = K.Q^T  (C: col=lan16=qrow, row=quad*4+reg=key)
// O^T = V^T.P^T (C: col=lan16=qrow, row=quad*4+reg=dim)
__global__ __launch_bounds__(256)
void attn_k(const ushort_t* __restrict__ qw, const ushort_t* __restrict__ kw,
            const ushort_t* __restrict__ vt, const float* __restrict__ lsc,
            const float* __restrict__ gtab, ushort_t* __restrict__ ctx)
{
    __shared__ __align__(16) ushort_t K_s[2][64][72];       // [buf][key][dim]
    __shared__ __align__(16) ushort_t VT_s[2][64][72];      // [buf][dim][key]
    __shared__ __align__(16) unsigned int Pp[4][2][16][36]; // [wave][qf][qrow16][key-pair]

    const int t     = threadIdx.x;
    const int wid   = t >> 6;     // 0..3
    const int lane  = t & 63;
    const int lan16 = lane & 15;
    const int quad  = lane >> 4;

    const int h  = blockIdx.x;
    const int qt = blockIdx.y;    // 0..15
    const int n  = blockIdx.z;
    const int q0 = qt * 128;

    const size_t headoff = ((size_t)(n * H_N + h)) * SEQ * DH;
    const ushort_t* qh  = qw + headoff;
    const ushort_t* kh  = kw + headoff;
    const ushort_t* vth = vt + headoff;

    float ls = lsc[h];
    const float lm = 4.60517018598809136804f;   // log(100)
    if (ls > lm) ls = lm;
    const float scale2 = __expf(ls) * 0.04419417382415921757f * LOG2E;

    const int qrow0 = q0 + wid * 32 + lan16;    // qf adds +16
    const float4* gt = (const float4*)gtab + (size_t)h * RELN + (qrow0 + 2047 - quad * 4);

    short8_t qb[2][2];
    #pragma unroll
    for (int qf = 0; qf < 2; qf++) {
        const ushort_t* src = qh + (size_t)(qrow0 + qf * 16) * DH + quad * 8;
        qb[qf][0] = *(const short8_t*)(src);
        qb[qf][1] = *(const short8_t*)(src + 32);
    }

    float l_run[2] = {0.f, 0.f};
    float4_t o[4][2];   // [dim-sub][qf]
    #pragma unroll
    for (int ds = 0; ds < 4; ds++)
        #pragma unroll
        for (int qf = 0; qf < 2; qf++) o[ds][qf] = (float4_t){0.f, 0.f, 0.f, 0.f};

    const int srow = t >> 2;        // 0..63
    const int sc   = (t & 3) * 16;  // ushort offset (32B span)
    const ushort_t* kbase = kh + (size_t)srow * DH + sc;
    const ushort_t* vbase = vth + (size_t)srow * SEQ + sc;

    // ---- prologue: stage tile 0 into buf 0, load its bias (even set)
    float4 b4E[2][4];
    {
        uint4 k0r = *(const uint4*)(kbase);
        uint4 k1r = *(const uint4*)(kbase + 8);
        uint4 v0r = *(const uint4*)(vbase);
        uint4 v1r = *(const uint4*)(vbase + 8);
        #pragma unroll
        for (int qf = 0; qf < 2; qf++)
            #pragma unroll
            for (int sub = 0; sub < 4; sub++) b4E[qf][sub] = gt[(qf - sub) * 16];
        *(uint4*)&K_s[0][srow][sc]      = k0r;
        *(uint4*)&K_s[0][srow][sc + 8]  = k1r;
        *(uint4*)&VT_s[0][srow][sc]     = v0r;
        *(uint4*)&VT_s[0][srow][sc + 8] = v1r;
    }
    __syncthreads();

// COMPUTE(B, B4): process current tile from static buffer literal B, bias B4.
#define COMPUTE(B, B4)                                                               \
  {                                                                                  \
    float4_t st[4][2];                                                               \
    _Pragma("unroll")                                                                \
    for (int sub = 0; sub < 4; sub++) {                                              \
        const ushort_t* kp_ = &K_s[B][sub * 16 + lan16][quad * 8];                   \
        short8_t ka0 = *(const short8_t*)(kp_);                                      \
        short8_t ka1 = *(const short8_t*)(kp_ + 32);                                 \
        _Pragma("unroll")                                                            \
        for (int qf = 0; qf < 2; qf++) {                                             \
            float4_t a = (float4_t){0.f, 0.f, 0.f, 0.f};                             \
            a = __builtin_amdgcn_mfma_f32_16x16x32_bf16(ka0, qb[qf][0], a, 0, 0, 0); \
            a = __builtin_amdgcn_mfma_f32_16x16x32_bf16(ka1, qb[qf][1], a, 0, 0, 0); \
            st[sub][qf] = a;                                                         \
        }                                                                            \
    }                                                                                \
    _Pragma("unroll")                                                                \
    for (int qf = 0; qf < 2; qf++) {                                                 \
        float ps = 0.f;                                                              \
        _Pragma("unroll")                                                            \
        for (int sub = 0; sub < 4; sub++) {                                          \
            float e0 = fexp2(st[sub][qf][0] * scale2 + B4[qf][sub].x);               \
            float e1 = fexp2(st[sub][qf][1] * scale2 + B4[qf][sub].y);               \
            float e2 = fexp2(st[sub][qf][2] * scale2 + B4[qf][sub].z);               \
            float e3 = fexp2(st[sub][qf][3] * scale2 + B4[qf][sub].w);               \
            ps += (e0 + e1) + (e2 + e3);                                             \
            uint2 pw;                                                                \
            pw.x = cvtpk_bf16(e0, e1);                                               \
            pw.y = cvtpk_bf16(e2, e3);                                               \
            *(uint2*)&Pp[wid][qf][lan16][sub * 8 + quad * 2] = pw;                   \
        }                                                                            \
        l_run[qf] += ps;                                                             \
    }                                                                                \
    asm volatile("s_waitcnt lgkmcnt(0)" ::: "memory");                               \
    _Pragma("unroll")                                                                \
    for (int ks = 0; ks < 2; ks++) {                                                 \
        short8_t pb[2];                                                              \
        _Pragma("unroll")                                                            \
        for (int qf = 0; qf < 2; qf++)                                               \
            pb[qf] = *(const short8_t*)&Pp[wid][qf][lan16][ks * 16 + quad * 4];      \
        _Pragma("unroll")                                                            \
        for (int ds = 0; ds < 4; ds++) {                                             \
            short8_t va = *(const short8_t*)&VT_s[B][ds * 16 + lan16][ks * 32 + quad * 8]; \
            _Pragma("unroll")                                                        \
            for (int qf = 0; qf < 2; qf++)                                           \
                o[ds][qf] = __builtin_amdgcn_mfma_f32_16x16x32_bf16(va, pb[qf], o[ds][qf], 0, 0, 0); \
        }                                                                            \
    }                                                                                \
  }

    #pragma unroll 1
    for (int it = 0; it < 16; it++) {
        const int j0a = it * 128;          // even tile (buf 0)

        // ---- half A: prefetch tile j0a+64, compute tile j0a from buf 0
        {
            uint4 kr0 = *(const uint4*)(kbase + (size_t)(j0a + 64) * DH);
            uint4 kr1 = *(const uint4*)(kbase + (size_t)(j0a + 64) * DH + 8);
            uint4 vr0 = *(const uint4*)(vbase + (j0a + 64));
            uint4 vr1 = *(const uint4*)(vbase + (j0a + 64) + 8);
            float4 b4O[2][4];
            {
                const float4* gtp = gt - (j0a + 64);
                #pragma unroll
                for (int qf = 0; qf < 2; qf++)
                    #pragma unroll
                    for (int sub = 0; sub < 4; sub++) b4O[qf][sub] = gtp[(qf - sub) * 16];
            }

            COMPUTE(0, b4E);

            *(uint4*)&K_s[1][srow][sc]      = kr0;
            *(uint4*)&K_s[1][srow][sc + 8]  = kr1;
            *(uint4*)&VT_s[1][srow][sc]     = vr0;
            *(uint4*)&VT_s[1][srow][sc + 8] = vr1;
            __syncthreads();

            // ---- half B: prefetch tile j0a+128 (guarded), compute tile j0a+64 from buf 1
            if (it < 15) {
                uint4 ke0 = *(const uint4*)(kbase + (size_t)(j0a + 128) * DH);
                uint4 ke1 = *(const uint4*)(kbase + (size_t)(j0a + 128) * DH + 8);
                uint4 ve0 = *(const uint4*)(vbase + (j0a + 128));
                uint4 ve1 = *(const uint4*)(vbase + (j0a + 128) + 8);
                {
                    const float4* gtp = gt - (j0a + 128);
                    #pragma unroll
                    for (int qf = 0; qf < 2; qf++)
                        #pragma unroll
                        for (int sub = 0; sub < 4; sub++) b4E[qf][sub] = gtp[(qf - sub) * 16];
                }

                COMPUTE(1, b4O);

                *(uint4*)&K_s[0][srow][sc]      = ke0;
                *(uint4*)&K_s[0][srow][sc + 8]  = ke1;
                *(uint4*)&VT_s[0][srow][sc]     = ve0;
                *(uint4*)&VT_s[0][srow][sc + 8] = ve1;
                __syncthreads();
            } else {
                COMPUTE(1, b4O);   // last tile: no prefetch, no write, no barrier
            }
        }
    }
#undef COMPUTE

    // epilogue: reduce l across quads; O^T col=lan16=qrow, row=quad*4+reg=dim; bf16 ctx
    #pragma unroll
    for (int qf = 0; qf < 2; qf++) {
        float l = l_run[qf];
        l += __shfl_xor(l, 16);
        l += __shfl_xor(l, 32);
        float inv = 1.0f / l;
        int row = qrow0 + qf * 16;
        size_t base = ((size_t)n * SEQ + row) * DM + h * DH;
        #pragma unroll
        for (int ds = 0; ds < 4; ds++) {
            uint2 p;
            p.x = cvtpk_bf16(o[ds][qf][0] * inv, o[ds][qf][1] * inv);
            p.y = cvtpk_bf16(o[ds][qf][2] * inv, o[ds][qf][3] * inv);
            *(uint2*)(ctx + base + ds * 16 + quad * 4) = p;
        }
    }
}

extern "C" void kernel_launch(void* const* d_in, const int* in_sizes, int n_in,
                              void* d_out, int out_size, void* d_ws, size_t ws_size,
                              hipStream_t stream) {
    const float* query = (const float*)d_in[0];
    const float* Wq  = (const float*)d_in[1];
    const float* bq  = (const float*)d_in[2];
    const float* Wk  = (const float*)d_in[3];
    const float* bk  = (const float*)d_in[4];
    const float* Wv  = (const float*)d_in[5];
    const float* bv  = (const float*)d_in[6];
    const float* Wp  = (const float*)d_in[7];
    const float* bp  = (const float*)d_in[8];
    const float* lsc = (const float*)d_in[9];
    const float* rpe = (const float*)d_in[10];

    const size_t QEL = (size_t)N_B * SEQ * DM;     // 4,194,304
    const size_t WEL = (size_t)DM * DM;            // 262,144
    char* ws = (char*)d_ws;
    ushort_t* q16  = (ushort_t*)(ws);              // bf16 query
    ushort_t* w16  = q16 + QEL;                    // Wq|Wk|Wv|Wp bf16 (qkv head-major permuted)
    float*    bcat = (float*)(w16 + 4 * WEL);      // 2048 floats (permuted to match)
    float*    gtab = bcat + 2048;                  // 8*4095 float4 = 512 KB
    ushort_t* qb   = (ushort_t*)(gtab + 4 * GTABN);
    ushort_t* kb   = qb + QEL;
    ushort_t* vtb  = kb + QEL;
    ushort_t* ctx  = vtb + QEL;                    // total ~44.5 MB

    const int PREPN = Q4 + 4 * W4 + 2048 + GTABN;
    prep<<<(PREPN + 255) / 256, 256, 0, stream>>>(
        query, Wq, Wk, Wv, Wp, bq, bk, bv, bp, rpe, q16, w16, bcat, gtab);

    dim3 g1((N_B * SEQ) / 128, 1536 / 128);        // (64, 12): rows on x -> A panels XCD-pinned
    mgemm<0><<<g1, 256, 0, stream>>>(q16, w16, bcat, qb, kb, vtb, nullptr);

    dim3 ga(H_N, SEQ / 128, N_B);                  // (8, 16, 4): lid%8 == h -> XCD co-residency
    attn_k<<<ga, 256, 0, stream>>>(qb, kb, vtb, lsc, gtab, ctx);

    dim3 g2((N_B * SEQ) / 128, DM / 64);           // (64, 8): 512 blocks, 2 blocks/CU
    mgemm1_k<<<g2, 256, 0, stream>>>(ctx, w16 + 3 * WEL, bcat + 1536, (float*)d_out);
}